// Round 8
// baseline (758.862 us; speedup 1.0000x reference)
//
#include <hip/hip_runtime.h>
#include <cstdint>
#include <cstddef>

#define HEADS 8
#define DH 64
#define DIM 512      // HEADS*DH
#define CIN 256
#define EPS 1e-5f
#define NB 64        // token-blocks per (batch, head) in K1
#define BATCH 2
#define NTOK 32768   // 8*64*64 tokens (fixed problem size)

#define XPAD 264     // x LDS row stride in shorts (528B = 33*16, all rows 16B-aligned)
#define TP 36        // ekT/vT LDS row stride in shorts (72B; 8B-aligned reads; conflict-free)

// floats to zero ahead of K1: ctx_un (B*8*64*64) + Ssum (B*8*64), contiguous
#define ZERO_F4 16640

typedef __attribute__((ext_vector_type(8))) short bf16x8;
typedef __attribute__((ext_vector_type(4))) float f32x4;

static __device__ __forceinline__ f32x4 mfma16(bf16x8 a, bf16x8 b, f32x4 c) {
  return __builtin_amdgcn_mfma_f32_16x16x32_bf16(a, b, c, 0, 0, 0);
}
static __device__ __forceinline__ unsigned short f2bf(float f) {
  unsigned int u = __float_as_uint(f);
  u += 0x7FFFu + ((u >> 16) & 1u);   // RNE (finite inputs only)
  return (unsigned short)(u >> 16);
}
static __device__ __forceinline__ float bf2f(unsigned short h) {
  return __uint_as_float(((unsigned int)h) << 16);
}
static __device__ __forceinline__ void split2(float f, unsigned short& hi, unsigned short& lo) {
  hi = f2bf(f);
  lo = f2bf(f - bf2f(hi));
}
// load bf16x8 from 8B-aligned LDS (two uint2 halves)
static __device__ __forceinline__ bf16x8 ld_b8(const unsigned short* p) {
  union { bf16x8 v; uint2 u[2]; } t;
  t.u[0] = *(const uint2*)p;
  t.u[1] = *(const uint2*)(p + 4);
  return t.v;
}

// ---------------------------------------------------------------------------
// P0a: pre-split x (f32) -> xhg/xlg (bf16 hi/lo), plain [b][n][c] layout.
// grid 4096 x 256, 4 float4 per thread, fully coalesced.
// ---------------------------------------------------------------------------
__global__ __launch_bounds__(256) void split_x(
    const float* __restrict__ x, unsigned short* __restrict__ xh,
    unsigned short* __restrict__ xl)
{
  const float4* xf = (const float4*)x;
  uint2* oh = (uint2*)xh;
  uint2* ol = (uint2*)xl;
  const int base = blockIdx.x * 256 + threadIdx.x;
#pragma unroll
  for (int j = 0; j < 4; ++j) {
    const size_t p = (size_t)base + (size_t)j * 1048576;
    const float4 v = xf[p];
    unsigned short h0,l0,h1,l1,h2,l2,h3,l3;
    split2(v.x,h0,l0); split2(v.y,h1,l1); split2(v.z,h2,l2); split2(v.w,h3,l3);
    oh[p] = make_uint2((unsigned)h0 | ((unsigned)h1 << 16),
                       (unsigned)h2 | ((unsigned)h3 << 16));
    ol[p] = make_uint2((unsigned)l0 | ((unsigned)l1 << 16),
                       (unsigned)l2 | ((unsigned)l3 << 16));
  }
}

// ---------------------------------------------------------------------------
// P0b: transpose+convert w_qkv -> wThi/wTlo (1536 x 256 bf16); zero ctx+Ssum.
// ---------------------------------------------------------------------------
__global__ __launch_bounds__(256) void prep_wT(
    const float* __restrict__ wqkv, unsigned short* __restrict__ wThi,
    unsigned short* __restrict__ wTlo, float* __restrict__ zero_base)
{
  __shared__ __align__(16) unsigned short thi[64][68];
  __shared__ __align__(16) unsigned short tlo[64][68];
  const int tid = threadIdx.x;
  const int f0 = (blockIdx.x >> 2) * 64;
  const int k0 = (blockIdx.x & 3) * 64;

  {
    const int gid = blockIdx.x * 256 + tid;
    if (gid < ZERO_F4)
      ((float4*)zero_base)[gid] = make_float4(0.f, 0.f, 0.f, 0.f);
  }
  {
    const int kl = tid >> 2;
    const int fc = (tid & 3) * 16;
#pragma unroll
    for (int i = 0; i < 4; ++i) {
      const float4 v = *(const float4*)(wqkv + (size_t)(k0 + kl) * (3 * DIM) + f0 + fc + i * 4);
      unsigned short h, l;
      split2(v.x, h, l); thi[kl][fc + i*4 + 0] = h; tlo[kl][fc + i*4 + 0] = l;
      split2(v.y, h, l); thi[kl][fc + i*4 + 1] = h; tlo[kl][fc + i*4 + 1] = l;
      split2(v.z, h, l); thi[kl][fc + i*4 + 2] = h; tlo[kl][fc + i*4 + 2] = l;
      split2(v.w, h, l); thi[kl][fc + i*4 + 3] = h; tlo[kl][fc + i*4 + 3] = l;
    }
  }
  __syncthreads();
  {
    const int fl = tid >> 2;
    const int kc = (tid & 3) * 16;
    unsigned int ph[8], pl[8];
#pragma unroll
    for (int m = 0; m < 8; ++m) {
      ph[m] = (unsigned)thi[kc + 2*m][fl] | ((unsigned)thi[kc + 2*m + 1][fl] << 16);
      pl[m] = (unsigned)tlo[kc + 2*m][fl] | ((unsigned)tlo[kc + 2*m + 1][fl] << 16);
    }
    unsigned int* dh = (unsigned int*)(wThi + (size_t)(f0 + fl) * CIN + k0 + kc);
    unsigned int* dl = (unsigned int*)(wTlo + (size_t)(f0 + fl) * CIN + k0 + kc);
#pragma unroll
    for (int m = 0; m < 8; ++m) { dh[m] = ph[m]; dl[m] = pl[m]; }
  }
}

// ---------------------------------------------------------------------------
// K1: split-bf16 k/v projection (MFMA) + split-bf16 ctx += E^T V (MFMA).
// grid 1024, 256 thr. XCD swizzle keeps 8 heads of one token-range on one L2.
// PRESPLIT: stage pre-split bf16 x (pure loads); else split in-kernel.
// TP=36 trims LDS to 52.2KB -> 3 blocks/CU; (256,3).
// ---------------------------------------------------------------------------
template<bool PRESPLIT>
__global__ __launch_bounds__(256, 3) void kv_ctx_mfma(
    const float* __restrict__ x,
    const unsigned short* __restrict__ xhg, const unsigned short* __restrict__ xlg,
    const unsigned short* __restrict__ wThi, const unsigned short* __restrict__ wTlo,
    float* __restrict__ ctx_un, float* __restrict__ Ssum)
{
  __shared__ __align__(16) unsigned short xhi[32 * XPAD];
  __shared__ __align__(16) unsigned short xlo[32 * XPAD];
  __shared__ __align__(16) unsigned short ekhi[64 * TP];
  __shared__ __align__(16) unsigned short eklo[64 * TP];
  __shared__ __align__(16) unsigned short vhs[64 * TP];
  __shared__ __align__(16) unsigned short vls[64 * TP];

  const int tid = threadIdx.x;
  const int L = blockIdx.x;
  const int tb = (((L >> 6) & 7) << 3) | (L & 7);
  const int h  = (L >> 3) & 7;
  const int b  = L >> 9;
  const int n0 = tb * (NTOK / NB);

  const int wave = tid >> 6;
  const int lane = tid & 63;
  const int lg = lane >> 4;
  const int lr = lane & 15;

  const bool isv = wave >= 2;
  const int cbase = (wave & 1) * 32;
  const int wrow_base = (isv ? 2 * DIM : DIM) + h * DH + cbase;
  const unsigned short* whB = wThi + (size_t)wrow_base * CIN;
  const unsigned short* wlB = wTlo + (size_t)wrow_base * CIN;

  const short one_bf = (short)0x3F80;
  const bf16x8 bones = {one_bf, one_bf, one_bf, one_bf, one_bf, one_bf, one_bf, one_bf};

  f32x4 ctx[4];
#pragma unroll
  for (int et = 0; et < 4; ++et) ctx[et] = (f32x4)0.f;
  f32x4 acc_s = (f32x4)0.f;

  const int srow = tid >> 3;        // 0..31
  const int cch  = tid & 7;         // 8 chunks-of-32-shorts per row

  uint4 ph[4], pl[4];               // presplit prefetch
  float4 pf[8];                     // fallback prefetch

  if constexpr (PRESPLIT) {
    const uint4* gh = (const uint4*)(xhg + ((size_t)b * NTOK + n0) * CIN);
    const uint4* gl = (const uint4*)(xlg + ((size_t)b * NTOK + n0) * CIN);
#pragma unroll
    for (int i = 0; i < 4; ++i) {
      ph[i] = gh[srow * 32 + cch + i * 8];
      pl[i] = gl[srow * 32 + cch + i * 8];
    }
  } else {
    const float4* xg0 = (const float4*)(x + ((size_t)b * NTOK + n0) * CIN);
#pragma unroll
    for (int i = 0; i < 8; ++i) pf[i] = xg0[srow * 64 + cch * 8 + i];
  }

#pragma unroll 1
  for (int sub = 0; sub < 16; ++sub) {
    // ---- write staged tile -> LDS ----
    if constexpr (PRESPLIT) {
#pragma unroll
      for (int i = 0; i < 4; ++i) {
        *(uint4*)(xhi + srow * XPAD + (cch + i * 8) * 8) = ph[i];
        *(uint4*)(xlo + srow * XPAD + (cch + i * 8) * 8) = pl[i];
      }
    } else {
      unsigned short* dh = xhi + srow * XPAD + cch * 32;
      unsigned short* dl = xlo + srow * XPAD + cch * 32;
#pragma unroll
      for (int i = 0; i < 8; ++i) {
        const float4 v = pf[i];
        unsigned short h0,l0,h1,l1,h2,l2,h3,l3;
        split2(v.x,h0,l0); split2(v.y,h1,l1); split2(v.z,h2,l2); split2(v.w,h3,l3);
        *(uint2*)(dh + i*4) = make_uint2((unsigned)h0 | ((unsigned)h1 << 16),
                                         (unsigned)h2 | ((unsigned)h3 << 16));
        *(uint2*)(dl + i*4) = make_uint2((unsigned)l0 | ((unsigned)l1 << 16),
                                         (unsigned)l2 | ((unsigned)l3 << 16));
      }
    }
    // ---- prefetch next tile (latency hides under proj+ctx) ----
    if (sub + 1 < 16) {
      const int nn = n0 + (sub + 1) * 32;
      if constexpr (PRESPLIT) {
        const uint4* gh = (const uint4*)(xhg + ((size_t)b * NTOK + nn) * CIN);
        const uint4* gl = (const uint4*)(xlg + ((size_t)b * NTOK + nn) * CIN);
#pragma unroll
        for (int i = 0; i < 4; ++i) {
          ph[i] = gh[srow * 32 + cch + i * 8];
          pl[i] = gl[srow * 32 + cch + i * 8];
        }
      } else {
        const float4* xg = (const float4*)(x + ((size_t)b * NTOK + nn) * CIN);
#pragma unroll
        for (int i = 0; i < 8; ++i) pf[i] = xg[srow * 64 + cch * 8 + i];
      }
    }
    __syncthreads();

    // ---- projection: 32 tok x 32 cols per wave, K=256, split-bf16 ----
    f32x4 acc[2][2];
#pragma unroll
    for (int rt = 0; rt < 2; ++rt)
#pragma unroll
      for (int ct = 0; ct < 2; ++ct) acc[rt][ct] = (f32x4)0.f;

#pragma unroll
    for (int kk = 0; kk < 8; ++kk) {
      const bf16x8 a0h = *(const bf16x8*)(xhi + (0 + lr) * XPAD + kk * 32 + lg * 8);
      const bf16x8 a1h = *(const bf16x8*)(xhi + (16 + lr) * XPAD + kk * 32 + lg * 8);
      const bf16x8 a0l = *(const bf16x8*)(xlo + (0 + lr) * XPAD + kk * 32 + lg * 8);
      const bf16x8 a1l = *(const bf16x8*)(xlo + (16 + lr) * XPAD + kk * 32 + lg * 8);
#pragma unroll
      for (int ct = 0; ct < 2; ++ct) {
        const int rofs = (ct * 16 + lr) * CIN + kk * 32 + lg * 8;
        const bf16x8 bwh = *(const bf16x8*)(whB + rofs);
        const bf16x8 bwl = *(const bf16x8*)(wlB + rofs);
        acc[0][ct] = mfma16(a0h, bwh, acc[0][ct]);
        acc[0][ct] = mfma16(a0h, bwl, acc[0][ct]);
        acc[0][ct] = mfma16(a0l, bwh, acc[0][ct]);
        acc[1][ct] = mfma16(a1h, bwh, acc[1][ct]);
        acc[1][ct] = mfma16(a1h, bwl, acc[1][ct]);
        acc[1][ct] = mfma16(a1l, bwh, acc[1][ct]);
      }
    }

    // ---- split + transposed scatter: ekT/vT[c][t] ----
#pragma unroll
    for (int rt = 0; rt < 2; ++rt)
#pragma unroll
      for (int ct = 0; ct < 2; ++ct) {
        unsigned short hh[4], ll[4];
#pragma unroll
        for (int r = 0; r < 4; ++r) {
          float f = acc[rt][ct][r];
          if (!isv) f = __expf(f);
          split2(f, hh[r], ll[r]);
        }
        const int c = cbase + ct * 16 + lr;
        const int t0 = rt * 16 + lg * 4;
        unsigned short* phd = (isv ? vhs : ekhi) + c * TP + t0;
        unsigned short* pld = (isv ? vls : eklo) + c * TP + t0;
        *(uint2*)phd = make_uint2((unsigned)hh[0] | ((unsigned)hh[1] << 16),
                                  (unsigned)hh[2] | ((unsigned)hh[3] << 16));
        *(uint2*)pld = make_uint2((unsigned)ll[0] | ((unsigned)ll[1] << 16),
                                  (unsigned)ll[2] | ((unsigned)ll[3] << 16));
      }
    __syncthreads();

    // ---- ctx += E^T V (split-bf16), S += E^T 1 ----
    {
      const int drow = wave * 16 + lr;
      const bf16x8 aeh = ld_b8(ekhi + drow * TP + lg * 8);
      const bf16x8 ael = ld_b8(eklo + drow * TP + lg * 8);
      acc_s = mfma16(aeh, bones, acc_s);
      acc_s = mfma16(ael, bones, acc_s);
#pragma unroll
      for (int et = 0; et < 4; ++et) {
        const bf16x8 bvh = ld_b8(vhs + (et * 16 + lr) * TP + lg * 8);
        const bf16x8 bvl = ld_b8(vls + (et * 16 + lr) * TP + lg * 8);
        ctx[et] = mfma16(aeh, bvh, ctx[et]);
        ctx[et] = mfma16(aeh, bvl, ctx[et]);
        ctx[et] = mfma16(ael, bvh, ctx[et]);
      }
    }
  }

  float* ctxb = ctx_un + ((size_t)b * HEADS + h) * DH * DH;
#pragma unroll
  for (int et = 0; et < 4; ++et)
#pragma unroll
    for (int r = 0; r < 4; ++r)
      atomicAdd(&ctxb[(wave * 16 + lg * 4 + r) * DH + et * 16 + lr], ctx[et][r]);
  if (lr == 0) {
#pragma unroll
    for (int r = 0; r < 4; ++r)
      atomicAdd(&Ssum[((size_t)b * HEADS + h) * DH + wave * 16 + lg * 4 + r], acc_s[r]);
  }
}

// ---------------------------------------------------------------------------
// K2: MT[b][c][f] = split_bf16( sum_e ctx[h,d,e]*(invN/S[d]) * w_out[h*64+e][c] )
// ---------------------------------------------------------------------------
__global__ __launch_bounds__(256) void m_kernel(
    const float* __restrict__ ctx_un, const float* __restrict__ Ssum,
    const float* __restrict__ wout, unsigned short* __restrict__ MThi,
    unsigned short* __restrict__ MTlo, float invN)
{
  const int blk = blockIdx.x;
  const int b = blk >> 5;
  const int f0 = (blk & 31) * 16;
  const int h = f0 / DH;
  const int c = threadIdx.x;
  const float* ctxb = ctx_un + ((size_t)b * HEADS + h) * DH * DH;
  const float* Sb   = Ssum + ((size_t)b * HEADS + h) * DH;
  float acc[16];
#pragma unroll
  for (int i = 0; i < 16; ++i) acc[i] = 0.f;
  for (int e = 0; e < DH; ++e) {
    const float wv = wout[(size_t)(h * DH + e) * CIN + c];
#pragma unroll
    for (int i = 0; i < 16; ++i) {
      const int d = (f0 + i) & (DH - 1);
      acc[i] += ctxb[d * DH + e] * wv;
    }
  }
  unsigned short* mh = MThi + ((size_t)b * CIN + c) * DIM;
  unsigned short* ml = MTlo + ((size_t)b * CIN + c) * DIM;
#pragma unroll
  for (int i = 0; i < 16; ++i) {
    const int d = (f0 + i) & (DH - 1);
    unsigned short hh, ll;
    split2(acc[i] * (invN / Sb[d]), hh, ll);
    mh[f0 + i] = hh;
    ml[f0 + i] = ll;
  }
}

// ---------------------------------------------------------------------------
// K3: 8 waves (512 thr), wave = head. GEMM1 acc 32 regs/wave; full q (32x512
// hi+lo) in 64KB LDS, XOR-swizzled (chunk ^= t&15); single-pass GEMM2 (no
// held-q registers). Phases: stage x -> GEMM1 -> softmax -> q to LDS ->
// GEMM2 -> bias -> LN -> store.
// ---------------------------------------------------------------------------
template<bool PRESPLIT>
__global__ __launch_bounds__(512, 4) void out_mfma(
    const float* __restrict__ x,
    const unsigned short* __restrict__ xhg, const unsigned short* __restrict__ xlg,
    const unsigned short* __restrict__ wThi, const unsigned short* __restrict__ wTlo,
    const unsigned short* __restrict__ MThi, const unsigned short* __restrict__ MTlo,
    const float* __restrict__ bout, const float* __restrict__ lnsc,
    float* __restrict__ out)
{
  __shared__ __align__(16) unsigned short buf[32768];   // exactly 64 KB, phase-multiplexed

  unsigned short* const xh  = buf;                 // [32][XPAD] during stage/GEMM1
  unsigned short* const xl  = buf + 32 * XPAD;
  unsigned short* const qhi = buf;                 // [32][512] swizzled during GEMM2
  unsigned short* const qlo = buf + 32 * 512;
  float* const redf = (float*)buf;                 // [8*32*2] + mus[32] + rss[32] after GEMM2

  const int tid = threadIdx.x;
  const int blk = blockIdx.x;
  const int b = blk / (NTOK / 32);
  const int n0 = (blk % (NTOK / 32)) * 32;

  const int wave = tid >> 6;      // 0..7 == head
  const int lane = tid & 63;
  const int lg = lane >> 4;
  const int lr = lane & 15;

  // ---- stage x (32 x 256, split hi/lo) ----
  {
    const int row = tid >> 4;     // 0..31
    const int cu  = tid & 15;
    if constexpr (PRESPLIT) {
      const uint4* gh = (const uint4*)(xhg + ((size_t)b * NTOK + n0) * CIN);
      const uint4* gl = (const uint4*)(xlg + ((size_t)b * NTOK + n0) * CIN);
#pragma unroll
      for (int i = 0; i < 2; ++i) {
        const int u = cu + i * 16;
        *(uint4*)(xh + row * XPAD + u * 8) = gh[row * 32 + u];
        *(uint4*)(xl + row * XPAD + u * 8) = gl[row * 32 + u];
      }
    } else {
      const float4* xg = (const float4*)(x + ((size_t)b * NTOK + n0) * CIN);
#pragma unroll
      for (int i = 0; i < 4; ++i) {
        const int u = cu + i * 16;
        const float4 v = xg[row * 64 + u];
        unsigned short h0,l0,h1,l1,h2,l2,h3,l3;
        split2(v.x,h0,l0); split2(v.y,h1,l1); split2(v.z,h2,l2); split2(v.w,h3,l3);
        *(uint2*)(xh + row*XPAD + u*4) = make_uint2((unsigned)h0 | ((unsigned)h1 << 16),
                                                    (unsigned)h2 | ((unsigned)h3 << 16));
        *(uint2*)(xl + row*XPAD + u*4) = make_uint2((unsigned)l0 | ((unsigned)l1 << 16),
                                                    (unsigned)l2 | ((unsigned)l3 << 16));
      }
    }
  }
  __syncthreads();

  // ---- GEMM1: q(32 x 64) for this wave's head, K=256, split-bf16 ----
  f32x4 q[2][4];
#pragma unroll
  for (int rt = 0; rt < 2; ++rt)
#pragma unroll
    for (int ct = 0; ct < 4; ++ct) q[rt][ct] = (f32x4)0.f;

#pragma unroll 2
  for (int kk = 0; kk < 8; ++kk) {
    const bf16x8 a0h = *(const bf16x8*)(xh + (0 + lr) * XPAD + kk * 32 + lg * 8);
    const bf16x8 a1h = *(const bf16x8*)(xh + (16 + lr) * XPAD + kk * 32 + lg * 8);
    const bf16x8 a0l = *(const bf16x8*)(xl + (0 + lr) * XPAD + kk * 32 + lg * 8);
    const bf16x8 a1l = *(const bf16x8*)(xl + (16 + lr) * XPAD + kk * 32 + lg * 8);
#pragma unroll
    for (int ct = 0; ct < 4; ++ct) {
      const size_t row = (size_t)(wave * 64 + ct * 16 + lr);
      const bf16x8 bwh = *(const bf16x8*)(wThi + row * CIN + kk * 32 + lg * 8);
      const bf16x8 bwl = *(const bf16x8*)(wTlo + row * CIN + kk * 32 + lg * 8);
      q[0][ct] = mfma16(a0h, bwh, q[0][ct]);
      q[0][ct] = mfma16(a0h, bwl, q[0][ct]);
      q[0][ct] = mfma16(a0l, bwh, q[0][ct]);
      q[1][ct] = mfma16(a1h, bwh, q[1][ct]);
      q[1][ct] = mfma16(a1h, bwl, q[1][ct]);
      q[1][ct] = mfma16(a1l, bwh, q[1][ct]);
    }
  }

  // ---- softmax over this head's 64 cols per token, then *1/8 ----
#pragma unroll
  for (int rt = 0; rt < 2; ++rt)
#pragma unroll
    for (int r = 0; r < 4; ++r) {
      float m0 = fmaxf(fmaxf(q[rt][0][r], q[rt][1][r]),
                       fmaxf(q[rt][2][r], q[rt][3][r]));
#pragma unroll
      for (int off = 1; off < 16; off <<= 1)
        m0 = fmaxf(m0, __shfl_xor(m0, off, 16));
      const float e0v = __expf(q[rt][0][r] - m0);
      const float e1v = __expf(q[rt][1][r] - m0);
      const float e2v = __expf(q[rt][2][r] - m0);
      const float e3v = __expf(q[rt][3][r] - m0);
      float s = e0v + e1v + e2v + e3v;
#pragma unroll
      for (int off = 1; off < 16; off <<= 1)
        s += __shfl_xor(s, off, 16);
      const float sc = 0.125f / s;
      q[rt][0][r] = e0v * sc;
      q[rt][1][r] = e1v * sc;
      q[rt][2][r] = e2v * sc;
      q[rt][3][r] = e3v * sc;
    }

  __syncthreads();   // all GEMM1 x-reads done; buf reusable for q

  // ---- q -> LDS, split bf16, swizzled: chunk(col>>3) ^= (t&15) ----
#pragma unroll
  for (int rt = 0; rt < 2; ++rt)
#pragma unroll
    for (int ct = 0; ct < 4; ++ct)
#pragma unroll
      for (int r = 0; r < 4; ++r) {
        const int t = rt * 16 + lg * 4 + r;
        const int col = wave * 64 + ct * 16 + lr;
        unsigned short hh, ll;
        split2(q[rt][ct][r], hh, ll);
        const int pos = t * 512 + ((((col >> 3) ^ (t & 15)) << 3) | (col & 7));
        qhi[pos] = hh;
        qlo[pos] = ll;
      }
  __syncthreads();

  // ---- GEMM2: y(32 x 32) per wave, K=512, single pass ----
  f32x4 y[2][2];
#pragma unroll
  for (int rt = 0; rt < 2; ++rt)
#pragma unroll
    for (int ct = 0; ct < 2; ++ct) y[rt][ct] = (f32x4)0.f;

  const unsigned short* mhB = MThi + (size_t)b * CIN * DIM;
  const unsigned short* mlB = MTlo + (size_t)b * CIN * DIM;

#pragma unroll 2
  for (int kk = 0; kk < 16; ++kk) {
    const int sw = (((kk * 4 + lg) ^ lr) << 3);
    const bf16x8 a0h = *(const bf16x8*)(qhi + (0 + lr) * 512 + sw);
    const bf16x8 a1h = *(const bf16x8*)(qhi + (16 + lr) * 512 + sw);
    const bf16x8 a0l = *(const bf16x8*)(qlo + (0 + lr) * 512 + sw);
    const bf16x8 a1l = *(const bf16x8*)(qlo + (16 + lr) * 512 + sw);
#pragma unroll
    for (int ct = 0; ct < 2; ++ct) {
      const size_t crow = (size_t)(wave * 32 + ct * 16 + lr);
      const bf16x8 bmh = *(const bf16x8*)(mhB + crow * DIM + kk * 32 + lg * 8);
      const bf16x8 bml = *(const bf16x8*)(mlB + crow * DIM + kk * 32 + lg * 8);
      y[0][ct] = mfma16(a0h, bmh, y[0][ct]);
      y[0][ct] = mfma16(a0h, bml, y[0][ct]);
      y[0][ct] = mfma16(a0l, bmh, y[0][ct]);
      y[1][ct] = mfma16(a1h, bmh, y[1][ct]);
      y[1][ct] = mfma16(a1h, bml, y[1][ct]);
      y[1][ct] = mfma16(a1l, bmh, y[1][ct]);
    }
  }

  // ---- +bias ----
#pragma unroll
  for (int ct = 0; ct < 2; ++ct) {
    const float bb = bout[wave * 32 + ct * 16 + lr];
#pragma unroll
    for (int rt = 0; rt < 2; ++rt)
#pragma unroll
      for (int r = 0; r < 4; ++r) y[rt][ct][r] += bb;
  }

  __syncthreads();   // all q reads done; buf reusable for LN scratch

  // ---- LN partials: each wave covers its 32 cols ----
#pragma unroll
  for (int rt = 0; rt < 2; ++rt)
#pragma unroll
    for (int r = 0; r < 4; ++r) {
      float ps = y[rt][0][r] + y[rt][1][r];
      float ps2 = y[rt][0][r]*y[rt][0][r] + y[rt][1][r]*y[rt][1][r];
#pragma unroll
      for (int off = 1; off < 16; off <<= 1) {
        ps  += __shfl_xor(ps,  off, 16);
        ps2 += __shfl_xor(ps2, off, 16);
      }
      if (lr == 0) {
        const int t = rt * 16 + lg * 4 + r;
        redf[(wave * 32 + t) * 2 + 0] = ps;
        redf[(wave * 32 + t) * 2 + 1] = ps2;
      }
    }
  __syncthreads();
  if (tid < 32) {
    float S1 = 0.f, S2 = 0.f;
#pragma unroll
    for (int w = 0; w < 8; ++w) {
      S1 += redf[(w * 32 + tid) * 2 + 0];
      S2 += redf[(w * 32 + tid) * 2 + 1];
    }
    const float mu = S1 * (1.f / CIN);
    const float var = S2 * (1.f / CIN) - mu * mu;
    redf[512 + tid] = mu;               // mus
    redf[544 + tid] = rsqrtf(var + EPS); // rss
  }
  __syncthreads();

  // ---- normalize + scale + store ----
  float* ob = out + ((size_t)b * NTOK + n0) * CIN;
#pragma unroll
  for (int ct = 0; ct < 2; ++ct) {
    const int c = wave * 32 + ct * 16 + lr;
    const float lsc = lnsc[c];
#pragma unroll
    for (int rt = 0; rt < 2; ++rt)
#pragma unroll
      for (int r = 0; r < 4; ++r) {
        const int t = rt * 16 + lg * 4 + r;
        ob[(size_t)t * CIN + c] = (y[rt][ct][r] - redf[512 + t]) * redf[544 + t] * lsc;
      }
  }
}

// ---------------------------------------------------------------------------
extern "C" void kernel_launch(void* const* d_in, const int* in_sizes, int n_in,
                              void* d_out, int out_size, void* d_ws, size_t ws_size,
                              hipStream_t stream) {
  const float* x     = (const float*)d_in[0];
  const float* wqkv  = (const float*)d_in[1];
  const float* wout  = (const float*)d_in[2];
  const float* bout  = (const float*)d_in[3];
  const float* lnsc  = (const float*)d_in[4];
  float* out = (float*)d_out;

  unsigned char* w = (unsigned char*)d_ws;
  unsigned short* wThi = (unsigned short*)(w + 0);          //  768 KB
  unsigned short* wTlo = (unsigned short*)(w + 786432);
  unsigned short* MThi = (unsigned short*)(w + 1572864);    //  512 KB
  unsigned short* MTlo = (unsigned short*)(w + 2097152);
  float* ctx_un = (float*)(w + 2621440);                    //  256 KB
  float* Ssum   = (float*)(w + 2883584);                    //    4 KB
  unsigned short* xhg = (unsigned short*)(w + 2887680);     //   32 MB
  unsigned short* xlg = (unsigned short*)(w + 2887680 + 33554432);
  const bool presplit = ws_size >= (size_t)2887680 + 2u * 33554432u;

  prep_wT<<<dim3(96), dim3(256), 0, stream>>>(wqkv, wThi, wTlo, ctx_un);
  if (presplit) {
    split_x<<<dim3(4096), dim3(256), 0, stream>>>(x, xhg, xlg);
    kv_ctx_mfma<true><<<dim3(BATCH * HEADS * NB), dim3(256), 0, stream>>>(
        x, xhg, xlg, wThi, wTlo, ctx_un, Ssum);
  } else {
    kv_ctx_mfma<false><<<dim3(BATCH * HEADS * NB), dim3(256), 0, stream>>>(
        x, xhg, xlg, wThi, wTlo, ctx_un, Ssum);
  }
  m_kernel<<<dim3(BATCH * 32), dim3(256), 0, stream>>>(
      ctx_un, Ssum, wout, MThi, MTlo, 1.0f / (float)NTOK);
  if (presplit) {
    out_mfma<true><<<dim3(BATCH * (NTOK / 32)), dim3(512), 0, stream>>>(
        x, xhg, xlg, wThi, wTlo, MThi, MTlo, bout, lnsc, out);
  } else {
    out_mfma<false><<<dim3(BATCH * (NTOK / 32)), dim3(512), 0, stream>>>(
        x, xhg, xlg, wThi, wTlo, MThi, MTlo, bout, lnsc, out);
  }
}

// Round 10
// 510.303 us; speedup vs baseline: 1.4871x; 1.4871x over previous
//
#include <hip/hip_runtime.h>
#include <cstdint>
#include <cstddef>

#define HEADS 8
#define DH 64
#define DIM 512      // HEADS*DH
#define CIN 256
#define EPS 1e-5f
#define NB 64        // token-blocks per (batch, head) in K1
#define BATCH 2
#define NTOK 32768   // 8*64*64 tokens (fixed problem size)

#define XPAD 264     // x LDS row stride in shorts (528B, 16B-aligned)
#define TP 40        // ekT/vT LDS row stride in shorts (80B, 16B-aligned)

#define ZERO_F4 16640   // (ctx_un + Ssum) float4 count

typedef __attribute__((ext_vector_type(8))) short bf16x8;
typedef __attribute__((ext_vector_type(4))) float f32x4;

static __device__ __forceinline__ f32x4 mfma16(bf16x8 a, bf16x8 b, f32x4 c) {
  return __builtin_amdgcn_mfma_f32_16x16x32_bf16(a, b, c, 0, 0, 0);
}
static __device__ __forceinline__ unsigned short f2bf(float f) {
  unsigned int u = __float_as_uint(f);
  u += 0x7FFFu + ((u >> 16) & 1u);   // RNE (finite inputs only)
  return (unsigned short)(u >> 16);
}
static __device__ __forceinline__ float bf2f(unsigned short h) {
  return __uint_as_float(((unsigned int)h) << 16);
}
static __device__ __forceinline__ void split2(float f, unsigned short& hi, unsigned short& lo) {
  hi = f2bf(f);
  lo = f2bf(f - bf2f(hi));
}

// ---------------------------------------------------------------------------
// P0: transpose+convert w_qkv -> wThi/wTlo (1536 x 256 bf16); zero ctx+Ssum.
// ---------------------------------------------------------------------------
__global__ __launch_bounds__(256) void prep_wT(
    const float* __restrict__ wqkv, unsigned short* __restrict__ wThi,
    unsigned short* __restrict__ wTlo, float* __restrict__ zero_base)
{
  __shared__ __align__(16) unsigned short thi[64][68];
  __shared__ __align__(16) unsigned short tlo[64][68];
  const int tid = threadIdx.x;
  const int f0 = (blockIdx.x >> 2) * 64;
  const int k0 = (blockIdx.x & 3) * 64;

  {
    const int gid = blockIdx.x * 256 + tid;
    if (gid < ZERO_F4)
      ((float4*)zero_base)[gid] = make_float4(0.f, 0.f, 0.f, 0.f);
  }
  {
    const int kl = tid >> 2;
    const int fc = (tid & 3) * 16;
#pragma unroll
    for (int i = 0; i < 4; ++i) {
      const float4 v = *(const float4*)(wqkv + (size_t)(k0 + kl) * (3 * DIM) + f0 + fc + i * 4);
      unsigned short h, l;
      split2(v.x, h, l); thi[kl][fc + i*4 + 0] = h; tlo[kl][fc + i*4 + 0] = l;
      split2(v.y, h, l); thi[kl][fc + i*4 + 1] = h; tlo[kl][fc + i*4 + 1] = l;
      split2(v.z, h, l); thi[kl][fc + i*4 + 2] = h; tlo[kl][fc + i*4 + 2] = l;
      split2(v.w, h, l); thi[kl][fc + i*4 + 3] = h; tlo[kl][fc + i*4 + 3] = l;
    }
  }
  __syncthreads();
  {
    const int fl = tid >> 2;
    const int kc = (tid & 3) * 16;
    unsigned int ph[8], pl[8];
#pragma unroll
    for (int m = 0; m < 8; ++m) {
      ph[m] = (unsigned)thi[kc + 2*m][fl] | ((unsigned)thi[kc + 2*m + 1][fl] << 16);
      pl[m] = (unsigned)tlo[kc + 2*m][fl] | ((unsigned)tlo[kc + 2*m + 1][fl] << 16);
    }
    unsigned int* dh = (unsigned int*)(wThi + (size_t)(f0 + fl) * CIN + k0 + kc);
    unsigned int* dl = (unsigned int*)(wTlo + (size_t)(f0 + fl) * CIN + k0 + kc);
#pragma unroll
    for (int m = 0; m < 8; ++m) { dh[m] = ph[m]; dl[m] = pl[m]; }
  }
}

// ---------------------------------------------------------------------------
// K1 (round-7 known-good): split-bf16 k/v projection + ctx += E^T V, MFMA.
// grid 1024, 256 thr, (256,2). XCD swizzle: 8 heads of one token-range share
// an XCD's L2 for x. float4 prefetch of next tile hides HBM latency under
// proj+ctx MFMA. Weights stream from L2 each sub.
// ---------------------------------------------------------------------------
__global__ __launch_bounds__(256, 2) void kv_ctx_mfma(
    const float* __restrict__ x,
    const unsigned short* __restrict__ wThi, const unsigned short* __restrict__ wTlo,
    float* __restrict__ ctx_un, float* __restrict__ Ssum)
{
  __shared__ __align__(16) unsigned short xhi[32 * XPAD];
  __shared__ __align__(16) unsigned short xlo[32 * XPAD];
  __shared__ __align__(16) unsigned short ekhi[64 * TP];
  __shared__ __align__(16) unsigned short eklo[64 * TP];
  __shared__ __align__(16) unsigned short vhs[64 * TP];
  __shared__ __align__(16) unsigned short vls[64 * TP];

  const int tid = threadIdx.x;
  const int L = blockIdx.x;
  const int tb = (((L >> 6) & 7) << 3) | (L & 7);
  const int h  = (L >> 3) & 7;
  const int b  = L >> 9;
  const int n0 = tb * (NTOK / NB);

  const int wave = tid >> 6;
  const int lane = tid & 63;
  const int lg = lane >> 4;
  const int lr = lane & 15;

  const bool isv = wave >= 2;
  const int cbase = (wave & 1) * 32;
  const int wrow_base = (isv ? 2 * DIM : DIM) + h * DH + cbase;
  const unsigned short* whB = wThi + (size_t)wrow_base * CIN;
  const unsigned short* wlB = wTlo + (size_t)wrow_base * CIN;

  const short one_bf = (short)0x3F80;
  const bf16x8 bones = {one_bf, one_bf, one_bf, one_bf, one_bf, one_bf, one_bf, one_bf};

  f32x4 ctx[4];
#pragma unroll
  for (int et = 0; et < 4; ++et) ctx[et] = (f32x4)0.f;
  f32x4 acc_s = (f32x4)0.f;

  const int srow = tid >> 3;            // 0..31
  const int c0f  = (tid & 7) * 32;      // float col base
  const float4* xg0 = (const float4*)(x + ((size_t)b * NTOK + n0) * CIN);

  float4 pf[8];
#pragma unroll
  for (int i = 0; i < 8; ++i) pf[i] = xg0[srow * 64 + (c0f >> 2) + i];

#pragma unroll 1
  for (int sub = 0; sub < 16; ++sub) {
    // ---- write staged regs -> split-bf16 LDS ----
    {
      unsigned short* dh = xhi + srow * XPAD + c0f;
      unsigned short* dl = xlo + srow * XPAD + c0f;
#pragma unroll
      for (int i = 0; i < 8; ++i) {
        const float4 v = pf[i];
        unsigned short h0,l0,h1,l1,h2,l2,h3,l3;
        split2(v.x,h0,l0); split2(v.y,h1,l1); split2(v.z,h2,l2); split2(v.w,h3,l3);
        *(uint2*)(dh + i*4) = make_uint2((unsigned)h0 | ((unsigned)h1 << 16),
                                         (unsigned)h2 | ((unsigned)h3 << 16));
        *(uint2*)(dl + i*4) = make_uint2((unsigned)l0 | ((unsigned)l1 << 16),
                                         (unsigned)l2 | ((unsigned)l3 << 16));
      }
    }
    // ---- issue next sub's loads (latency hides under proj+ctx) ----
    if (sub + 1 < 16) {
      const float4* xg = xg0 + (size_t)(sub + 1) * 32 * 64;
#pragma unroll
      for (int i = 0; i < 8; ++i) pf[i] = xg[srow * 64 + (c0f >> 2) + i];
    }
    __syncthreads();

    // ---- projection: 32 tok x 32 cols per wave, K=256, split-bf16 ----
    f32x4 acc[2][2];
#pragma unroll
    for (int rt = 0; rt < 2; ++rt)
#pragma unroll
      for (int ct = 0; ct < 2; ++ct) acc[rt][ct] = (f32x4)0.f;

#pragma unroll
    for (int kk = 0; kk < 8; ++kk) {
      const bf16x8 a0h = *(const bf16x8*)(xhi + (0 + lr) * XPAD + kk * 32 + lg * 8);
      const bf16x8 a1h = *(const bf16x8*)(xhi + (16 + lr) * XPAD + kk * 32 + lg * 8);
      const bf16x8 a0l = *(const bf16x8*)(xlo + (0 + lr) * XPAD + kk * 32 + lg * 8);
      const bf16x8 a1l = *(const bf16x8*)(xlo + (16 + lr) * XPAD + kk * 32 + lg * 8);
#pragma unroll
      for (int ct = 0; ct < 2; ++ct) {
        const int rofs = (ct * 16 + lr) * CIN + kk * 32 + lg * 8;
        const bf16x8 bwh = *(const bf16x8*)(whB + rofs);
        const bf16x8 bwl = *(const bf16x8*)(wlB + rofs);
        acc[0][ct] = mfma16(a0h, bwh, acc[0][ct]);
        acc[0][ct] = mfma16(a0h, bwl, acc[0][ct]);
        acc[0][ct] = mfma16(a0l, bwh, acc[0][ct]);
        acc[1][ct] = mfma16(a1h, bwh, acc[1][ct]);
        acc[1][ct] = mfma16(a1h, bwl, acc[1][ct]);
        acc[1][ct] = mfma16(a1l, bwh, acc[1][ct]);
      }
    }

    // ---- split + transposed scatter: ekT/vT[c][t] ----
#pragma unroll
    for (int rt = 0; rt < 2; ++rt)
#pragma unroll
      for (int ct = 0; ct < 2; ++ct) {
        unsigned short hh[4], ll[4];
#pragma unroll
        for (int r = 0; r < 4; ++r) {
          float f = acc[rt][ct][r];
          if (!isv) f = __expf(f);
          split2(f, hh[r], ll[r]);
        }
        const int c = cbase + ct * 16 + lr;
        const int t0 = rt * 16 + lg * 4;
        unsigned short* phd = (isv ? vhs : ekhi) + c * TP + t0;
        unsigned short* pld = (isv ? vls : eklo) + c * TP + t0;
        *(uint2*)phd = make_uint2((unsigned)hh[0] | ((unsigned)hh[1] << 16),
                                  (unsigned)hh[2] | ((unsigned)hh[3] << 16));
        *(uint2*)pld = make_uint2((unsigned)ll[0] | ((unsigned)ll[1] << 16),
                                  (unsigned)ll[2] | ((unsigned)ll[3] << 16));
      }
    __syncthreads();

    // ---- ctx += E^T V (split-bf16), S += E^T 1 ----
    {
      const int drow = wave * 16 + lr;
      const bf16x8 aeh = *(const bf16x8*)(ekhi + drow * TP + lg * 8);
      const bf16x8 ael = *(const bf16x8*)(eklo + drow * TP + lg * 8);
      acc_s = mfma16(aeh, bones, acc_s);
      acc_s = mfma16(ael, bones, acc_s);
#pragma unroll
      for (int et = 0; et < 4; ++et) {
        const bf16x8 bvh = *(const bf16x8*)(vhs + (et * 16 + lr) * TP + lg * 8);
        const bf16x8 bvl = *(const bf16x8*)(vls + (et * 16 + lr) * TP + lg * 8);
        ctx[et] = mfma16(aeh, bvh, ctx[et]);
        ctx[et] = mfma16(aeh, bvl, ctx[et]);
        ctx[et] = mfma16(ael, bvh, ctx[et]);
      }
    }
  }

  float* ctxb = ctx_un + ((size_t)b * HEADS + h) * DH * DH;
#pragma unroll
  for (int et = 0; et < 4; ++et)
#pragma unroll
    for (int r = 0; r < 4; ++r)
      atomicAdd(&ctxb[(wave * 16 + lg * 4 + r) * DH + et * 16 + lr], ctx[et][r]);
  if (lr == 0) {
#pragma unroll
    for (int r = 0; r < 4; ++r)
      atomicAdd(&Ssum[((size_t)b * HEADS + h) * DH + wave * 16 + lg * 4 + r], acc_s[r]);
  }
}

// ---------------------------------------------------------------------------
// K2: MT[b][c][f] = split_bf16( sum_e ctx[h,d,e]*(invN/S[d]) * w_out[h*64+e][c] )
// ---------------------------------------------------------------------------
__global__ __launch_bounds__(256) void m_kernel(
    const float* __restrict__ ctx_un, const float* __restrict__ Ssum,
    const float* __restrict__ wout, unsigned short* __restrict__ MThi,
    unsigned short* __restrict__ MTlo, float invN)
{
  const int blk = blockIdx.x;
  const int b = blk >> 5;
  const int f0 = (blk & 31) * 16;
  const int h = f0 / DH;
  const int c = threadIdx.x;
  const float* ctxb = ctx_un + ((size_t)b * HEADS + h) * DH * DH;
  const float* Sb   = Ssum + ((size_t)b * HEADS + h) * DH;
  float acc[16];
#pragma unroll
  for (int i = 0; i < 16; ++i) acc[i] = 0.f;
  for (int e = 0; e < DH; ++e) {
    const float wv = wout[(size_t)(h * DH + e) * CIN + c];
#pragma unroll
    for (int i = 0; i < 16; ++i) {
      const int d = (f0 + i) & (DH - 1);
      acc[i] += ctxb[d * DH + e] * wv;
    }
  }
  unsigned short* mh = MThi + ((size_t)b * CIN + c) * DIM;
  unsigned short* ml = MTlo + ((size_t)b * CIN + c) * DIM;
#pragma unroll
  for (int i = 0; i < 16; ++i) {
    const int d = (f0 + i) & (DH - 1);
    unsigned short hh, ll;
    split2(acc[i] * (invN / Sb[d]), hh, ll);
    mh[f0 + i] = hh;
    ml[f0 + i] = ll;
  }
}

// ---------------------------------------------------------------------------
// K3: 8 waves (512 thr), wave = head. Batch->XCD-half swizzle: b=(L>>2)&1 so
// XCDs 0..3 serve b=0, 4..7 serve b=1 -> per-XCD weight set 2.5MB < 4MB L2.
// Full q (32x512 hi+lo) in 64KB LDS, XOR-swizzled; single-pass GEMM2.
// ---------------------------------------------------------------------------
__global__ __launch_bounds__(512, 4) void out_mfma(
    const float* __restrict__ x,
    const unsigned short* __restrict__ wThi, const unsigned short* __restrict__ wTlo,
    const unsigned short* __restrict__ MThi, const unsigned short* __restrict__ MTlo,
    const float* __restrict__ bout, const float* __restrict__ lnsc,
    float* __restrict__ out)
{
  __shared__ __align__(16) unsigned short buf[32768];   // 64 KB, phase-multiplexed

  unsigned short* const xh  = buf;                 // [32][XPAD] during stage/GEMM1
  unsigned short* const xl  = buf + 32 * XPAD;
  unsigned short* const qhi = buf;                 // [32][512] swizzled during GEMM2
  unsigned short* const qlo = buf + 32 * 512;
  float* const redf = (float*)buf;                 // LN scratch after GEMM2

  const int tid = threadIdx.x;
  const int L = blockIdx.x;
  const int b = (L >> 2) & 1;                      // XCD half <-> batch
  const int n0 = (((L >> 3) << 2) | (L & 3)) * 32; // tile within batch

  const int wave = tid >> 6;      // 0..7 == head
  const int lane = tid & 63;
  const int lg = lane >> 4;
  const int lr = lane & 15;

  // ---- stage x (32 x 256, split hi/lo) ----
  {
    const int row = tid >> 4;     // 0..31
    const int cu  = tid & 15;
    const float4* xg = (const float4*)(x + ((size_t)b * NTOK + n0) * CIN);
#pragma unroll
    for (int i = 0; i < 4; ++i) {
      const int u = cu + i * 16;
      const float4 v = xg[row * 64 + u];
      unsigned short h0,l0,h1,l1,h2,l2,h3,l3;
      split2(v.x,h0,l0); split2(v.y,h1,l1); split2(v.z,h2,l2); split2(v.w,h3,l3);
      *(uint2*)(xh + row*XPAD + u*4) = make_uint2((unsigned)h0 | ((unsigned)h1 << 16),
                                                  (unsigned)h2 | ((unsigned)h3 << 16));
      *(uint2*)(xl + row*XPAD + u*4) = make_uint2((unsigned)l0 | ((unsigned)l1 << 16),
                                                  (unsigned)l2 | ((unsigned)l3 << 16));
    }
  }
  __syncthreads();

  // ---- GEMM1: q(32 x 64) for this wave's head, K=256, split-bf16 ----
  f32x4 q[2][4];
#pragma unroll
  for (int rt = 0; rt < 2; ++rt)
#pragma unroll
    for (int ct = 0; ct < 4; ++ct) q[rt][ct] = (f32x4)0.f;

#pragma unroll 2
  for (int kk = 0; kk < 8; ++kk) {
    const bf16x8 a0h = *(const bf16x8*)(xh + (0 + lr) * XPAD + kk * 32 + lg * 8);
    const bf16x8 a1h = *(const bf16x8*)(xh + (16 + lr) * XPAD + kk * 32 + lg * 8);
    const bf16x8 a0l = *(const bf16x8*)(xl + (0 + lr) * XPAD + kk * 32 + lg * 8);
    const bf16x8 a1l = *(const bf16x8*)(xl + (16 + lr) * XPAD + kk * 32 + lg * 8);
#pragma unroll
    for (int ct = 0; ct < 4; ++ct) {
      const size_t row = (size_t)(wave * 64 + ct * 16 + lr);
      const bf16x8 bwh = *(const bf16x8*)(wThi + row * CIN + kk * 32 + lg * 8);
      const bf16x8 bwl = *(const bf16x8*)(wTlo + row * CIN + kk * 32 + lg * 8);
      q[0][ct] = mfma16(a0h, bwh, q[0][ct]);
      q[0][ct] = mfma16(a0h, bwl, q[0][ct]);
      q[0][ct] = mfma16(a0l, bwh, q[0][ct]);
      q[1][ct] = mfma16(a1h, bwh, q[1][ct]);
      q[1][ct] = mfma16(a1h, bwl, q[1][ct]);
      q[1][ct] = mfma16(a1l, bwh, q[1][ct]);
    }
  }

  // ---- softmax over this head's 64 cols per token, then *1/8 ----
#pragma unroll
  for (int rt = 0; rt < 2; ++rt)
#pragma unroll
    for (int r = 0; r < 4; ++r) {
      float m0 = fmaxf(fmaxf(q[rt][0][r], q[rt][1][r]),
                       fmaxf(q[rt][2][r], q[rt][3][r]));
#pragma unroll
      for (int off = 1; off < 16; off <<= 1)
        m0 = fmaxf(m0, __shfl_xor(m0, off, 16));
      const float e0v = __expf(q[rt][0][r] - m0);
      const float e1v = __expf(q[rt][1][r] - m0);
      const float e2v = __expf(q[rt][2][r] - m0);
      const float e3v = __expf(q[rt][3][r] - m0);
      float s = e0v + e1v + e2v + e3v;
#pragma unroll
      for (int off = 1; off < 16; off <<= 1)
        s += __shfl_xor(s, off, 16);
      const float sc = 0.125f / s;
      q[rt][0][r] = e0v * sc;
      q[rt][1][r] = e1v * sc;
      q[rt][2][r] = e2v * sc;
      q[rt][3][r] = e3v * sc;
    }

  __syncthreads();   // all GEMM1 x-reads done; buf reusable for q

  // ---- q -> LDS, split bf16, swizzled: chunk(col>>3) ^= (t&15) ----
#pragma unroll
  for (int rt = 0; rt < 2; ++rt)
#pragma unroll
    for (int ct = 0; ct < 4; ++ct)
#pragma unroll
      for (int r = 0; r < 4; ++r) {
        const int t = rt * 16 + lg * 4 + r;
        const int col = wave * 64 + ct * 16 + lr;
        unsigned short hh, ll;
        split2(q[rt][ct][r], hh, ll);
        const int pos = t * 512 + ((((col >> 3) ^ (t & 15)) << 3) | (col & 7));
        qhi[pos] = hh;
        qlo[pos] = ll;
      }
  __syncthreads();

  // ---- GEMM2: y(32 x 32) per wave, K=512, single pass ----
  f32x4 y[2][2];
#pragma unroll
  for (int rt = 0; rt < 2; ++rt)
#pragma unroll
    for (int ct = 0; ct < 2; ++ct) y[rt][ct] = (f32x4)0.f;

  const unsigned short* mhB = MThi + (size_t)b * CIN * DIM;
  const unsigned short* mlB = MTlo + (size_t)b * CIN * DIM;

#pragma unroll 2
  for (int kk = 0; kk < 16; ++kk) {
    const int sw = (((kk * 4 + lg) ^ lr) << 3);
    const bf16x8 a0h = *(const bf16x8*)(qhi + (0 + lr) * 512 + sw);
    const bf16x8 a1h = *(const bf16x8*)(qhi + (16 + lr) * 512 + sw);
    const bf16x8 a0l = *(const bf16x8*)(qlo + (0 + lr) * 512 + sw);
    const bf16x8 a1l = *(const bf16x8*)(qlo + (16 + lr) * 512 + sw);
#pragma unroll
    for (int ct = 0; ct < 2; ++ct) {
      const size_t crow = (size_t)(wave * 32 + ct * 16 + lr);
      const bf16x8 bmh = *(const bf16x8*)(mhB + crow * DIM + kk * 32 + lg * 8);
      const bf16x8 bml = *(const bf16x8*)(mlB + crow * DIM + kk * 32 + lg * 8);
      y[0][ct] = mfma16(a0h, bmh, y[0][ct]);
      y[0][ct] = mfma16(a0h, bml, y[0][ct]);
      y[0][ct] = mfma16(a0l, bmh, y[0][ct]);
      y[1][ct] = mfma16(a1h, bmh, y[1][ct]);
      y[1][ct] = mfma16(a1h, bml, y[1][ct]);
      y[1][ct] = mfma16(a1l, bmh, y[1][ct]);
    }
  }

  // ---- +bias ----
#pragma unroll
  for (int ct = 0; ct < 2; ++ct) {
    const float bb = bout[wave * 32 + ct * 16 + lr];
#pragma unroll
    for (int rt = 0; rt < 2; ++rt)
#pragma unroll
      for (int r = 0; r < 4; ++r) y[rt][ct][r] += bb;
  }

  __syncthreads();   // all q reads done; buf reusable for LN scratch

  // ---- LN partials: each wave covers its 32 cols ----
#pragma unroll
  for (int rt = 0; rt < 2; ++rt)
#pragma unroll
    for (int r = 0; r < 4; ++r) {
      float ps = y[rt][0][r] + y[rt][1][r];
      float ps2 = y[rt][0][r]*y[rt][0][r] + y[rt][1][r]*y[rt][1][r];
#pragma unroll
      for (int off = 1; off < 16; off <<= 1) {
        ps  += __shfl_xor(ps,  off, 16);
        ps2 += __shfl_xor(ps2, off, 16);
      }
      if (lr == 0) {
        const int t = rt * 16 + lg * 4 + r;
        redf[(wave * 32 + t) * 2 + 0] = ps;
        redf[(wave * 32 + t) * 2 + 1] = ps2;
      }
    }
  __syncthreads();
  if (tid < 32) {
    float S1 = 0.f, S2 = 0.f;
#pragma unroll
    for (int w = 0; w < 8; ++w) {
      S1 += redf[(w * 32 + tid) * 2 + 0];
      S2 += redf[(w * 32 + tid) * 2 + 1];
    }
    const float mu = S1 * (1.f / CIN);
    const float var = S2 * (1.f / CIN) - mu * mu;
    redf[512 + tid] = mu;
    redf[544 + tid] = rsqrtf(var + EPS);
  }
  __syncthreads();

  // ---- normalize + scale + store ----
  float* ob = out + ((size_t)b * NTOK + n0) * CIN;
#pragma unroll
  for (int ct = 0; ct < 2; ++ct) {
    const int c = wave * 32 + ct * 16 + lr;
    const float lsc = lnsc[c];
#pragma unroll
    for (int rt = 0; rt < 2; ++rt)
#pragma unroll
      for (int r = 0; r < 4; ++r) {
        const int t = rt * 16 + lg * 4 + r;
        ob[(size_t)t * CIN + c] = (y[rt][ct][r] - redf[512 + t]) * redf[544 + t] * lsc;
      }
  }
}

// ---------------------------------------------------------------------------
extern "C" void kernel_launch(void* const* d_in, const int* in_sizes, int n_in,
                              void* d_out, int out_size, void* d_ws, size_t ws_size,
                              hipStream_t stream) {
  const float* x     = (const float*)d_in[0];
  const float* wqkv  = (const float*)d_in[1];
  const float* wout  = (const float*)d_in[2];
  const float* bout  = (const float*)d_in[3];
  const float* lnsc  = (const float*)d_in[4];
  float* out = (float*)d_out;

  unsigned char* w = (unsigned char*)d_ws;
  unsigned short* wThi = (unsigned short*)(w + 0);          //  768 KB
  unsigned short* wTlo = (unsigned short*)(w + 786432);
  unsigned short* MThi = (unsigned short*)(w + 1572864);    //  512 KB each
  unsigned short* MTlo = (unsigned short*)(w + 2097152);
  float* ctx_un = (float*)(w + 2621440);                    //  256 KB
  float* Ssum   = (float*)(w + 2883584);                    //    4 KB

  prep_wT<<<dim3(96), dim3(256), 0, stream>>>(wqkv, wThi, wTlo, ctx_un);
  kv_ctx_mfma<<<dim3(BATCH * HEADS * NB), dim3(256), 0, stream>>>(
      x, wThi, wTlo, ctx_un, Ssum);
  m_kernel<<<dim3(BATCH * 32), dim3(256), 0, stream>>>(
      ctx_un, Ssum, wout, MThi, MTlo, 1.0f / (float)NTOK);
  out_mfma<<<dim3(BATCH * (NTOK / 32)), dim3(512), 0, stream>>>(
      x, wThi, wTlo, MThi, MTlo, bout, lnsc, out);
}